// Round 3
// baseline (520.066 us; speedup 1.0000x reference)
//
#include <hip/hip_runtime.h>
#include <hip/hip_bf16.h>

typedef __bf16 bf16_t;
typedef __bf16 bf16x8 __attribute__((ext_vector_type(8)));
typedef __bf16 bf16x4 __attribute__((ext_vector_type(4)));
typedef __bf16 bf16x2 __attribute__((ext_vector_type(2)));
typedef float  f32x4  __attribute__((ext_vector_type(4)));

#define T_TOK 1024
#define DDIM  1024
#define FDIM  2048
#define NEXP  16
#define MAXR  192   // max tokens handled per expert (cnt ~ 128 +/- 11)

// ---------------- workspace layout (bytes), peak 21.1 MB ----------------
// [0, 64)        : int cnt[NEXP]                (memset each call)
// [1024, +64K)   : int   entry[NEXP][T_TOK]     (value = t*2 + slot)
// [66560, +64K)  : float entry_w[NEXP][T_TOK]
// [132096, +8M)  : OVERLAY: xg[NEXP][MAXR][DDIM] bf16 (gather..ffn1)
//                  then    partial[2][T_TOK][DDIM] f32 (ffn2..add)
// [8520704, +12.6M): bf16 fuse[NEXP][MAXR][FDIM]
#define WS_ENTRY_OFF   1024
#define WS_ENTRYW_OFF  66560
#define WS_XG_OFF      132096
#define WS_PART_OFF    132096
#define WS_FUSE_OFF    8520704

#define GLL16(g, l) __builtin_amdgcn_global_load_lds(                      \
    (const __attribute__((address_space(1))) unsigned int*)(g),            \
    (__attribute__((address_space(3))) unsigned int*)(l), 16, 0, 0)

// pipeline sync helpers (T3/T4: counted vmcnt, loads live across barriers)
#define FENCE()   asm volatile("" ::: "memory")
#define WAITVM(N) asm volatile("s_waitcnt vmcnt(" #N ")" ::: "memory")
#define WAITLG()  asm volatile("s_waitcnt lgkmcnt(0)" ::: "memory")
#define SCHEDB()  __builtin_amdgcn_sched_barrier(0)
#define SBAR()    __builtin_amdgcn_s_barrier()

// ---------------- router: 4 tokens per block (256 thr) ----------------
// rw is staged per 256-row d-tile into padded LDS (row stride 20 f32 ->
// 16B-aligned float4 reads, conflict-free) -- kills the 64-lane 4B@64B-stride
// scatter of the old per-token version. Per-lane accumulation order is
// bit-identical to the previous (harness-passing) version.
__global__ __launch_bounds__(256) void router_kernel(
    const float* __restrict__ x, const float* __restrict__ rw,
    int* __restrict__ cnt, int* __restrict__ entry, float* __restrict__ entry_w)
{
    __shared__ float rws[256][20];
    const int tid  = threadIdx.x;
    const int wave = tid >> 6;
    const int lane = tid & 63;
    const int t    = blockIdx.x * 4 + wave;

    float acc[NEXP];
#pragma unroll
    for (int e = 0; e < NEXP; ++e) acc[e] = 0.f;

    for (int tile = 0; tile < 4; ++tile) {
        const int d0 = tile * 256;
        // stage rw rows [d0, d0+256) : thread tid -> row d0+tid (64 B)
        {
            const float4* src = (const float4*)(rw + (size_t)(d0 + tid) * NEXP);
            float4 a = src[0], b = src[1], c = src[2], d = src[3];
            *(float4*)&rws[tid][0]  = a;
            *(float4*)&rws[tid][4]  = b;
            *(float4*)&rws[tid][8]  = c;
            *(float4*)&rws[tid][12] = d;
        }
        __syncthreads();
#pragma unroll
        for (int i = 0; i < 4; ++i) {
            const int row = i * 64 + lane;
            const float xv = x[(size_t)t * DDIM + d0 + row];
#pragma unroll
            for (int e4 = 0; e4 < 4; ++e4) {
                const float4 rv = *(const float4*)&rws[row][e4 * 4];
                acc[e4 * 4 + 0] += xv * rv.x;
                acc[e4 * 4 + 1] += xv * rv.y;
                acc[e4 * 4 + 2] += xv * rv.z;
                acc[e4 * 4 + 3] += xv * rv.w;
            }
        }
        __syncthreads();
    }
#pragma unroll
    for (int e = 0; e < NEXP; ++e) {
        float v = acc[e];
        for (int off = 32; off > 0; off >>= 1) v += __shfl_down(v, off);
        acc[e] = v;
    }
    if (lane == 0) {
        int i0 = -1, i1 = -1;
        float v0 = -1e30f, v1 = -1e30f;
#pragma unroll
        for (int e = 0; e < NEXP; ++e) {
            const float v = acc[e];
            if (v > v0)      { v1 = v0; i1 = i0; v0 = v; i0 = e; }
            else if (v > v1) { v1 = v;  i1 = e; }
        }
        const float e1 = __expf(v1 - v0);
        const float w0 = 1.f / (1.f + e1);
        const float w1 = e1 / (1.f + e1);
        int p = atomicAdd(&cnt[i0], 1);
        entry[i0 * T_TOK + p] = t * 2 + 0;
        entry_w[i0 * T_TOK + p] = w0;
        p = atomicAdd(&cnt[i1], 1);
        entry[i1 * T_TOK + p] = t * 2 + 1;
        entry_w[i1 * T_TOK + p] = w1;
    }
}

// ---------------- gather: x -> expert-local bf16 xg[e][i][d] ----------------
// grid (NEXP, MAXR/4), 256 thr; 4 rows per block.
__global__ __launch_bounds__(256) void gather_kernel(
    const float* __restrict__ x, const int* __restrict__ cnt,
    const int* __restrict__ entry, bf16_t* __restrict__ xg)
{
    const int e  = blockIdx.x;
    const int i0 = blockIdx.y * 4;
    const int tid = threadIdx.x;
    int n_tok = cnt[e]; if (n_tok > MAXR) n_tok = MAXR;
#pragma unroll
    for (int rr = 0; rr < 4; ++rr) {
        const int i = i0 + rr;
        bf16x4 v4;
        v4[0] = (bf16_t)0.f; v4[1] = (bf16_t)0.f; v4[2] = (bf16_t)0.f; v4[3] = (bf16_t)0.f;
        if (i < n_tok) {
            const int tok = entry[e * T_TOK + i] >> 1;
            const float4 v = *(const float4*)(x + (size_t)tok * DDIM + tid * 4);
            v4[0] = (bf16_t)v.x; v4[1] = (bf16_t)v.y; v4[2] = (bf16_t)v.z; v4[3] = (bf16_t)v.w;
        }
        *(bf16x4*)(xg + ((size_t)e * MAXR + i) * DDIM + tid * 4) = v4;
    }
}

// ---------------- phase 1: gating+up MFMA GEMM + silu-fuse ----------------
// grid (16, 64) = 1024 blocks -> 4 blocks/CU (was 2: the round-2 counters
// showed 20% occupancy with ALL pipes <20% => latency/concurrency-bound).
// BM=192, BN=32, BK=32, 256 thr, LDS 35 KB, __launch_bounds__(256,4).
// Block id = e + f*16 => all blocks of expert e land on XCD e%8 => xg[e]
// (384 KB x 2 experts) stays L2-resident per XCD.
// Counted-vmcnt pipeline: per iter per wave L_B=8 (4j x {g,u}) + G_A=3 GLL.
// Ledger at loop head: G_A(t)=3 + L_B(t+1)=8 + G_A(t+1)=3 = 14 outstanding
// -> WAITVM(11) drains exactly G_A(t); WAITVM(3) drains L_B(t+1).
// In-order vmcnt retirement makes any compiler-inserted extra drain safe.
__global__ __launch_bounds__(256, 4) void ffn1_kernel(
    const bf16_t* __restrict__ xg,
    const float* __restrict__ wg, const float* __restrict__ wu,
    const int* __restrict__ cnt, const int* __restrict__ entry,
    bf16_t* __restrict__ fuse)
{
    const int e  = blockIdx.x;
    const int f0 = blockIdx.y * 32;
    int n_tok = cnt[e]; if (n_tok > MAXR) n_tok = MAXR;

    __shared__ __align__(16) bf16_t As[2][MAXR][32];   // 24 KB
    __shared__ __align__(16) bf16_t Bgs[2][32][40];    // 5 KB (pad 8)
    __shared__ __align__(16) bf16_t Bus[2][32][40];    // 5 KB
    __shared__ int sem[MAXR];

    const int tid  = threadIdx.x;
    const int wave = tid >> 6;
    const int lane = tid & 63;
    const int r    = lane & 15;
    const int q    = lane >> 4;
    const int arow = lane >> 2;
    const int slot = (lane & 3) ^ (arow & 3);     // A k-chunk src swizzle (involution)
    const int bcol = lane & 31;                    // B col within 32-wide f-panel
    const int brow0 = wave * 8 + ((lane >> 5) << 2);  // first of 4 B k-rows

    const bf16_t* xg_e = xg + (size_t)e * MAXR * DDIM;
    const float* wg_p = wg + (size_t)e * DDIM * FDIM + (size_t)brow0 * FDIM + f0 + bcol;
    const float* wu_p = wu + (size_t)e * DDIM * FDIM + (size_t)brow0 * FDIM + f0 + bcol;

    if (tid < MAXR) sem[tid] = (tid < n_tok) ? entry[e * T_TOK + tid] : -1;

    float rg[4], ru[4];
    // ---- prologue: L_B(0) = 8 loads
#pragma unroll
    for (int j = 0; j < 4; ++j) { rg[j] = wg_p[(size_t)j * FDIM]; ru[j] = wu_p[(size_t)j * FDIM]; }
    FENCE();
    // ---- G_A(0) -> As[0]
#pragma unroll
    for (int c = 0; c < 3; ++c) {
        const int rowb = wave * 48 + c * 16;
        const bf16_t* g = xg_e + (size_t)(rowb + arow) * DDIM + slot * 8;
        GLL16(g, &As[0][rowb][0] + lane * 8);
    }
    FENCE();
    WAITVM(3);                       // L_B(0) done (G_A(0)=3 still outstanding)
    {
        bf16x4 pg, pu;
#pragma unroll
        for (int j = 0; j < 4; ++j) { pg[j] = (bf16_t)rg[j]; pu[j] = (bf16_t)ru[j]; }
        *(bf16x4*)&Bgs[0][bcol][brow0] = pg;
        *(bf16x4*)&Bus[0][bcol][brow0] = pu;
    }
    // ---- L_B(1)
    wg_p += (size_t)32 * FDIM; wu_p += (size_t)32 * FDIM;
#pragma unroll
    for (int j = 0; j < 4; ++j) { rg[j] = wg_p[(size_t)j * FDIM]; ru[j] = wu_p[(size_t)j * FDIM]; }
    FENCE();
    // ---- G_A(1) -> As[1]
#pragma unroll
    for (int c = 0; c < 3; ++c) {
        const int rowb = wave * 48 + c * 16;
        const bf16_t* g = xg_e + (size_t)(rowb + arow) * DDIM + 32 + slot * 8;
        GLL16(g, &As[1][rowb][0] + lane * 8);
    }
    FENCE();
    WAITLG();                        // Bs[0] pack visible
    SBAR();

    f32x4 accg[3][2], accu[3][2];
#pragma unroll
    for (int a = 0; a < 3; ++a)
#pragma unroll
        for (int b = 0; b < 2; ++b) {
            accg[a][b] = (f32x4){0.f, 0.f, 0.f, 0.f};
            accu[a][b] = (f32x4){0.f, 0.f, 0.f, 0.f};
        }

    for (int t = 0; t < 32; ++t) {
        const int cur = t & 1;
        // drain G_A(t): issued after it = L_B(t+1)=8 + G_A(t+1)=3 = 11.
        if (t == 31) { WAITVM(0); } else { WAITVM(11); }
        SCHEDB();
        bf16x8 af[3], bg[2], bu[2];
#pragma unroll
        for (int mt = 0; mt < 3; ++mt) {
            const int m = wave * 48 + mt * 16 + r;
            af[mt] = *(const bf16x8*)&As[cur][m][(q ^ (r & 3)) * 8];
        }
#pragma unroll
        for (int nt = 0; nt < 2; ++nt) {
            bg[nt] = *(const bf16x8*)&Bgs[cur][nt * 16 + r][q * 8];
            bu[nt] = *(const bf16x8*)&Bus[cur][nt * 16 + r][q * 8];
        }
        if (t < 31) {
            WAITVM(3);               // L_B(t+1) done (G_A(t+1)=3 outstanding)
            bf16x4 pg, pu;
#pragma unroll
            for (int j = 0; j < 4; ++j) { pg[j] = (bf16_t)rg[j]; pu[j] = (bf16_t)ru[j]; }
            *(bf16x4*)&Bgs[cur ^ 1][bcol][brow0] = pg;
            *(bf16x4*)&Bus[cur ^ 1][bcol][brow0] = pu;
        }
        WAITLG();                    // frags in regs; pack visible; As[cur] reads done
        SCHEDB();
        if (t < 30) {
            // prefetch t+2: L_B then G_A -> As[cur] (own As[cur] reads drained)
            wg_p += (size_t)32 * FDIM; wu_p += (size_t)32 * FDIM;
#pragma unroll
            for (int j = 0; j < 4; ++j) { rg[j] = wg_p[(size_t)j * FDIM]; ru[j] = wu_p[(size_t)j * FDIM]; }
            FENCE();
            const int kk = (t + 2) * 32;
#pragma unroll
            for (int c = 0; c < 3; ++c) {
                const int rowb = wave * 48 + c * 16;
                const bf16_t* g = xg_e + (size_t)(rowb + arow) * DDIM + kk + slot * 8;
                GLL16(g, &As[cur][rowb][0] + lane * 8);
            }
            FENCE();
        }
        __builtin_amdgcn_s_setprio(1);
#pragma unroll
        for (int mt = 0; mt < 3; ++mt)
#pragma unroll
            for (int nt = 0; nt < 2; ++nt) {
                accg[mt][nt] = __builtin_amdgcn_mfma_f32_16x16x32_bf16(af[mt], bg[nt], accg[mt][nt], 0, 0, 0);
                accu[mt][nt] = __builtin_amdgcn_mfma_f32_16x16x32_bf16(af[mt], bu[nt], accu[mt][nt], 0, 0, 0);
            }
        __builtin_amdgcn_s_setprio(0);
        SBAR();
    }

    // epilogue: silu(g)*u -> fuse[e][m][f] (bf16), zeros for padded rows
    bf16_t* fuse_e = fuse + (size_t)e * MAXR * FDIM + f0;
#pragma unroll
    for (int mt = 0; mt < 3; ++mt) {
#pragma unroll
        for (int j = 0; j < 4; ++j) {
            const int m = wave * 48 + mt * 16 + q * 4 + j;
            const bool valid = sem[m] >= 0;
            bf16_t* dst = fuse_e + (size_t)m * FDIM;
#pragma unroll
            for (int nt = 0; nt < 2; ++nt) {
                const float g = accg[mt][nt][j];
                const float u = accu[mt][nt][j];
                const float h = valid ? (g / (1.f + __expf(-g))) * u : 0.f;
                dst[nt * 16 + r] = (bf16_t)h;
            }
        }
    }
}

// ---------------- phase 2: down MFMA GEMM, weighted -> partial ----------------
// grid (16, 64) = 1024 blocks -> 4 blocks/CU. BM=192, BN=16, BK=32, 64 iters.
// LDS 28 KB. Block id = e + d*16 => expert e on XCD e%8 => fuse[e] (768 KB x2)
// L2-resident; adjacent d-panels share the XCD so 64-B B segments don't
// double-fetch 128-B lines.
// Ledger: per iter L_B=2, G_A=3; head outstanding = 3+2+3 = 8 -> WAITVM(5)
// drains G_A(t); WAITVM(3) drains L_B(t+1).
__global__ __launch_bounds__(256, 4) void ffn2_kernel(
    const bf16_t* __restrict__ fuse, const float* __restrict__ wd,
    const int* __restrict__ cnt, const int* __restrict__ entry,
    const float* __restrict__ entry_w, float* __restrict__ partial)
{
    const int e  = blockIdx.x;
    const int d0 = blockIdx.y * 16;
    int n_tok = cnt[e]; if (n_tok > MAXR) n_tok = MAXR;

    __shared__ __align__(16) bf16_t As[2][MAXR][32];   // 24 KB
    __shared__ __align__(16) bf16_t Bs[2][16][40];     // 2.5 KB (pad 8)
    __shared__ int   sem[MAXR];
    __shared__ float sw[MAXR];

    const int tid  = threadIdx.x;
    const int wave = tid >> 6;
    const int lane = tid & 63;
    const int r    = lane & 15;
    const int q    = lane >> 4;
    const int arow = lane >> 2;
    const int slot = (lane & 3) ^ (arow & 3);
    const int bcol = lane & 15;                       // d col within 16-wide panel
    const int brow0 = wave * 8 + ((lane >> 4) << 1);  // first of 2 B k-rows

    const bf16_t* fu_e = fuse + (size_t)e * MAXR * FDIM;
    const float* wd_p = wd + (size_t)e * FDIM * DDIM + (size_t)brow0 * DDIM + d0 + bcol;

    if (tid < MAXR) {
        sem[tid] = (tid < n_tok) ? entry[e * T_TOK + tid] : -1;
        sw[tid]  = (tid < n_tok) ? entry_w[e * T_TOK + tid] : 0.f;
    }

    float rb[2];
    // ---- prologue: L_B(0) = 2 loads
#pragma unroll
    for (int j = 0; j < 2; ++j) rb[j] = wd_p[(size_t)j * DDIM];
    FENCE();
    // ---- G_A(0) -> As[0]
#pragma unroll
    for (int c = 0; c < 3; ++c) {
        const int rowb = wave * 48 + c * 16;
        const bf16_t* g = fu_e + (size_t)(rowb + arow) * FDIM + slot * 8;
        GLL16(g, &As[0][rowb][0] + lane * 8);
    }
    FENCE();
    WAITVM(3);                       // L_B(0) done (G_A(0)=3 outstanding)
    {
        bf16x2 pb;
        pb[0] = (bf16_t)rb[0]; pb[1] = (bf16_t)rb[1];
        *(bf16x2*)&Bs[0][bcol][brow0] = pb;
    }
    // ---- L_B(1)
    wd_p += (size_t)32 * DDIM;
#pragma unroll
    for (int j = 0; j < 2; ++j) rb[j] = wd_p[(size_t)j * DDIM];
    FENCE();
    // ---- G_A(1) -> As[1]
#pragma unroll
    for (int c = 0; c < 3; ++c) {
        const int rowb = wave * 48 + c * 16;
        const bf16_t* g = fu_e + (size_t)(rowb + arow) * FDIM + 32 + slot * 8;
        GLL16(g, &As[1][rowb][0] + lane * 8);
    }
    FENCE();
    WAITLG();
    SBAR();

    f32x4 acc[3];
#pragma unroll
    for (int a = 0; a < 3; ++a) acc[a] = (f32x4){0.f, 0.f, 0.f, 0.f};

    for (int t = 0; t < 64; ++t) {
        const int cur = t & 1;
        // drain G_A(t): issued after it = L_B(t+1)=2 + G_A(t+1)=3 = 5.
        if (t == 63) { WAITVM(0); } else { WAITVM(5); }
        SCHEDB();
        bf16x8 af[3], bb;
#pragma unroll
        for (int mt = 0; mt < 3; ++mt) {
            const int m = wave * 48 + mt * 16 + r;
            af[mt] = *(const bf16x8*)&As[cur][m][(q ^ (r & 3)) * 8];
        }
        bb = *(const bf16x8*)&Bs[cur][r][q * 8];
        if (t < 63) {
            WAITVM(3);               // L_B(t+1) done (G_A(t+1)=3 outstanding)
            bf16x2 pb;
            pb[0] = (bf16_t)rb[0]; pb[1] = (bf16_t)rb[1];
            *(bf16x2*)&Bs[cur ^ 1][bcol][brow0] = pb;
        }
        WAITLG();
        SCHEDB();
        if (t < 62) {
            wd_p += (size_t)32 * DDIM;
#pragma unroll
            for (int j = 0; j < 2; ++j) rb[j] = wd_p[(size_t)j * DDIM];
            FENCE();
            const int kk = (t + 2) * 32;
#pragma unroll
            for (int c = 0; c < 3; ++c) {
                const int rowb = wave * 48 + c * 16;
                const bf16_t* g = fu_e + (size_t)(rowb + arow) * FDIM + kk + slot * 8;
                GLL16(g, &As[cur][rowb][0] + lane * 8);
            }
            FENCE();
        }
        __builtin_amdgcn_s_setprio(1);
#pragma unroll
        for (int mt = 0; mt < 3; ++mt)
            acc[mt] = __builtin_amdgcn_mfma_f32_16x16x32_bf16(af[mt], bb, acc[mt], 0, 0, 0);
        __builtin_amdgcn_s_setprio(0);
        SBAR();
    }

#pragma unroll
    for (int mt = 0; mt < 3; ++mt) {
#pragma unroll
        for (int j = 0; j < 4; ++j) {
            const int m = wave * 48 + mt * 16 + q * 4 + j;
            const int em = sem[m];
            if (em < 0) continue;
            const int t = em >> 1;
            const int sl = em & 1;
            const float w = sw[m];
            float* dst = partial + ((size_t)sl * T_TOK + t) * DDIM + d0;
            dst[r] = acc[mt][j] * w;
        }
    }
}

// ---------------- phase 3: out = partial[0] + partial[1] ----------------
__global__ __launch_bounds__(256) void add_kernel(
    const float* __restrict__ partial, float* __restrict__ out)
{
    const int i = blockIdx.x * blockDim.x + threadIdx.x;   // over T*D/4
    const float4 a = ((const float4*)partial)[i];
    const float4 b = ((const float4*)(partial + (size_t)T_TOK * DDIM))[i];
    float4 o;
    o.x = a.x + b.x; o.y = a.y + b.y; o.z = a.z + b.z; o.w = a.w + b.w;
    ((float4*)out)[i] = o;
}

extern "C" void kernel_launch(void* const* d_in, const int* in_sizes, int n_in,
                              void* d_out, int out_size, void* d_ws, size_t ws_size,
                              hipStream_t stream) {
    const float* x  = (const float*)d_in[0];
    const float* rw = (const float*)d_in[1];
    const float* wg = (const float*)d_in[2];
    const float* wu = (const float*)d_in[3];
    const float* wd = (const float*)d_in[4];
    float* out = (float*)d_out;

    char* ws = (char*)d_ws;
    int*    cnt     = (int*)ws;
    int*    entry   = (int*)(ws + WS_ENTRY_OFF);
    float*  entry_w = (float*)(ws + WS_ENTRYW_OFF);
    bf16_t* xg      = (bf16_t*)(ws + WS_XG_OFF);
    float*  partial = (float*)(ws + WS_PART_OFF);   // overlays xg (disjoint lifetime)
    bf16_t* fuse    = (bf16_t*)(ws + WS_FUSE_OFF);

    hipMemsetAsync(cnt, 0, 64, stream);

    router_kernel<<<T_TOK / 4, 256, 0, stream>>>(x, rw, cnt, entry, entry_w);

    gather_kernel<<<dim3(NEXP, MAXR / 4), 256, 0, stream>>>(x, cnt, entry, xg);

    ffn1_kernel<<<dim3(NEXP, FDIM / 32), 256, 0, stream>>>(
        xg, wg, wu, cnt, entry, fuse);

    ffn2_kernel<<<dim3(NEXP, DDIM / 16), 256, 0, stream>>>(
        fuse, wd, cnt, entry, entry_w, partial);

    add_kernel<<<(T_TOK * DDIM / 4) / 256, 256, 0, stream>>>(partial, out);
}